// Round 1
// baseline (588.249 us; speedup 1.0000x reference)
//
#include <hip/hip_runtime.h>
#include <cstdint>

// ---------------------------------------------------------------------------
// FM4Bio transformer layer on MI355X (gfx950).
// Pipeline: LN1 -> QKV GEMM (+RoPE) -> flash attention -> Wo GEMM (+resid)
//           -> LN2 -> W1 GEMM -> swiglu -> W2 GEMM (+resid)
// All GEMMs: bf16 MFMA 16x16x32, 128x128 tile, global_load_lds staging (m97).
// ---------------------------------------------------------------------------

typedef __bf16 bf16;
typedef __bf16 bf16x8 __attribute__((ext_vector_type(8)));
typedef float f32x4 __attribute__((ext_vector_type(4)));

#define B_ 2
#define S_ 2048
#define DM_ 1024
#define H_ 16
#define HD_ 64
#define INTER_ 4096

#define MFMA(a, b, c) __builtin_amdgcn_mfma_f32_16x16x32_bf16(a, b, c, 0, 0, 0)

__device__ __forceinline__ void cp16(void* lds, const void* g) {
  __builtin_amdgcn_global_load_lds(
      (const __attribute__((address_space(1))) void*)(uintptr_t)g,
      (__attribute__((address_space(3))) void*)(uint32_t)(uintptr_t)lds,
      16, 0, 0);
}

// ---------------------------------------------------------------------------
// Weight transpose: in fp32 [K][N] -> out bf16 [N][K]
// ---------------------------------------------------------------------------
__global__ void transpose_f32_bf16(const float* __restrict__ in,
                                   bf16* __restrict__ out, int K, int N) {
  __shared__ float tile[32][33];
  int n0 = blockIdx.x * 32, k0 = blockIdx.y * 32;
  int tx = threadIdx.x, ty = threadIdx.y;  // 32 x 8
#pragma unroll
  for (int i = 0; i < 32; i += 8)
    tile[ty + i][tx] = in[(size_t)(k0 + ty + i) * N + n0 + tx];
  __syncthreads();
#pragma unroll
  for (int i = 0; i < 32; i += 8)
    out[(size_t)(n0 + ty + i) * K + k0 + tx] = (bf16)tile[tx][ty + i];
}

// bf16 [K][N] -> bf16 [N][K], batched over blockIdx.z (for V -> V^T per head)
__global__ void transpose_bf16(const bf16* __restrict__ in,
                               bf16* __restrict__ out, int K, int N) {
  __shared__ bf16 tile[32][33];
  const size_t mo = (size_t)blockIdx.z * K * N;
  int n0 = blockIdx.x * 32, k0 = blockIdx.y * 32;
  int tx = threadIdx.x, ty = threadIdx.y;
#pragma unroll
  for (int i = 0; i < 32; i += 8)
    tile[ty + i][tx] = in[mo + (size_t)(k0 + ty + i) * N + n0 + tx];
  __syncthreads();
#pragma unroll
  for (int i = 0; i < 32; i += 8)
    out[mo + (size_t)(n0 + ty + i) * K + k0 + tx] = tile[tx][ty + i];
}

// ---------------------------------------------------------------------------
// LayerNorm: fp32 [rows][1024] -> bf16 [rows][1024]
// ---------------------------------------------------------------------------
__global__ __launch_bounds__(256) void ln_bf16(const float* __restrict__ x,
                                               const float* __restrict__ g,
                                               const float* __restrict__ bta,
                                               bf16* __restrict__ out) {
  int row = blockIdx.x;
  int tid = threadIdx.x;
  const float4* xr = (const float4*)(x + (size_t)row * DM_);
  float4 v = xr[tid];
  float s1 = v.x + v.y + v.z + v.w;
  float s2 = v.x * v.x + v.y * v.y + v.z * v.z + v.w * v.w;
#pragma unroll
  for (int off = 32; off; off >>= 1) {
    s1 += __shfl_xor(s1, off);
    s2 += __shfl_xor(s2, off);
  }
  __shared__ float rA[4], rB[4];
  int wave = tid >> 6, lane = tid & 63;
  if (!lane) { rA[wave] = s1; rB[wave] = s2; }
  __syncthreads();
  float t1 = rA[0] + rA[1] + rA[2] + rA[3];
  float t2 = rB[0] + rB[1] + rB[2] + rB[3];
  float mean = t1 * (1.0f / DM_);
  float var = t2 * (1.0f / DM_) - mean * mean;
  float rstd = rsqrtf(var + 1e-5f);
  int col = tid * 4;
  float4 gv = ((const float4*)g)[tid];
  float4 bv = ((const float4*)bta)[tid];
  bf16* o = out + (size_t)row * DM_ + col;
  o[0] = (bf16)((v.x - mean) * rstd * gv.x + bv.x);
  o[1] = (bf16)((v.y - mean) * rstd * gv.y + bv.y);
  o[2] = (bf16)((v.z - mean) * rstd * gv.z + bv.z);
  o[3] = (bf16)((v.w - mean) * rstd * gv.w + bv.w);
}

// ---------------------------------------------------------------------------
// swiglu: h bf16 [M][2*INTER] -> act bf16 [M][INTER]
// ---------------------------------------------------------------------------
__global__ __launch_bounds__(256) void swiglu_kernel(const bf16* __restrict__ h,
                                                     bf16* __restrict__ act) {
  size_t idx = ((size_t)blockIdx.x * 256 + threadIdx.x) * 8;
  size_t m = idx >> 12;           // / INTER_
  int n = (int)(idx & (INTER_ - 1));
  bf16x8 a = *(const bf16x8*)(h + m * (2 * INTER_) + n);
  bf16x8 b = *(const bf16x8*)(h + m * (2 * INTER_) + INTER_ + n);
  bf16x8 r;
#pragma unroll
  for (int j = 0; j < 8; ++j) {
    float x0 = (float)a[j];
    float x1 = (float)b[j];
    float sg = x1 / (1.0f + __expf(-x1));
    r[j] = (bf16)(x0 * sg);
  }
  *(bf16x8*)(act + m * INTER_ + n) = r;
}

// ---------------------------------------------------------------------------
// GEMM: C[M,N] = A[M,K](bf16) * Bt[N,K]^T(bf16), fused epilogues.
// EPI 0: +bias, RoPE, write bf16 [B,H,S,HD]
// EPI 1: +bias, write bf16 [B,H,S,HD]
// EPI 2: +bias +resid(fp32 [M,N]), write fp32 [M,N]
// EPI 3: +bias, write bf16 [M,N]
// ---------------------------------------------------------------------------
template <int EPI>
__global__ __launch_bounds__(256, 2) void gemm_bt(
    const bf16* __restrict__ A, const bf16* __restrict__ Bt,
    const float* __restrict__ bias, const float* __restrict__ rope,
    const float* __restrict__ resid, void* __restrict__ outp, int N, int K) {
  __shared__ __align__(16) bf16 As[128 * 32];
  __shared__ __align__(16) bf16 Bs[128 * 32];
  const int tid = threadIdx.x;
  const int lane = tid & 63, wave = tid >> 6;
  const int c = lane & 15, quad = lane >> 4;
  const int wr = wave >> 1, wc = wave & 1;
  const int bm0 = blockIdx.y * 128, bn0 = blockIdx.x * 128;

  f32x4 acc[4][4];
  const f32x4 z4 = {0.f, 0.f, 0.f, 0.f};
#pragma unroll
  for (int i = 0; i < 4; ++i)
#pragma unroll
    for (int j = 0; j < 4; ++j) acc[i][j] = z4;

  for (int k0 = 0; k0 < K; k0 += 32) {
    __syncthreads();
#pragma unroll
    for (int it = 0; it < 2; ++it) {
      int idx = tid + it * 256;       // 0..511 16B chunks
      int row = idx >> 2, ch = idx & 3;
      cp16(As + (size_t)idx * 8, A + (size_t)(bm0 + row) * K + k0 + ch * 8);
      cp16(Bs + (size_t)idx * 8, Bt + (size_t)(bn0 + row) * K + k0 + ch * 8);
    }
    __syncthreads();
    bf16x8 af[4], bfr[4];
#pragma unroll
    for (int ti = 0; ti < 4; ++ti)
      af[ti] = *(const bf16x8*)(As + (wr * 64 + ti * 16 + c) * 32 + quad * 8);
#pragma unroll
    for (int tj = 0; tj < 4; ++tj)
      bfr[tj] = *(const bf16x8*)(Bs + (wc * 64 + tj * 16 + c) * 32 + quad * 8);
#pragma unroll
    for (int ti = 0; ti < 4; ++ti)
#pragma unroll
      for (int tj = 0; tj < 4; ++tj)
        acc[ti][tj] = MFMA(af[ti], bfr[tj], acc[ti][tj]);
  }

  if constexpr (EPI == 2) {
    float* o = (float*)outp;
#pragma unroll
    for (int ti = 0; ti < 4; ++ti)
#pragma unroll
      for (int r = 0; r < 4; ++r) {
        int gm = bm0 + wr * 64 + ti * 16 + quad * 4 + r;
        const float* rrow = resid + (size_t)gm * N;
        float* orow = o + (size_t)gm * N;
#pragma unroll
        for (int tj = 0; tj < 4; ++tj) {
          int gn = bn0 + wc * 64 + tj * 16 + c;
          orow[gn] = acc[ti][tj][r] + bias[gn] + rrow[gn];
        }
      }
  } else if constexpr (EPI == 3) {
    bf16* o = (bf16*)outp;
#pragma unroll
    for (int ti = 0; ti < 4; ++ti)
#pragma unroll
      for (int r = 0; r < 4; ++r) {
        int gm = bm0 + wr * 64 + ti * 16 + quad * 4 + r;
        bf16* orow = o + (size_t)gm * N;
#pragma unroll
        for (int tj = 0; tj < 4; ++tj) {
          int gn = bn0 + wc * 64 + tj * 16 + c;
          orow[gn] = (bf16)(acc[ti][tj][r] + bias[gn]);
        }
      }
  } else {
    // heads layout (with optional RoPE): out[b][h][s][hd]
    bf16* o = (bf16*)outp;
#pragma unroll
    for (int ti = 0; ti < 4; ++ti)
#pragma unroll
      for (int r = 0; r < 4; ++r) {
        int gm = bm0 + wr * 64 + ti * 16 + quad * 4 + r;
        int s = gm & (S_ - 1);
        int b = gm >> 11;
#pragma unroll
        for (int tj = 0; tj < 4; ++tj) {
          int gn = bn0 + wc * 64 + tj * 16 + c;
          int hd = gn & (HD_ - 1);
          int h = gn >> 6;
          float val = acc[ti][tj][r] + bias[gn];
          if constexpr (EPI == 0) {
            // rotate_half over full head dim (pairs hd <-> hd+-32)
            float part = (tj < 2) ? -(acc[ti][tj + 2][r] + bias[gn + 32])
                                  : (acc[ti][tj - 2][r] + bias[gn - 32]);
            float fr = rope[s * HD_ + hd];
            float sn, cs;
            __sincosf(fr, &sn, &cs);
            val = val * cs + part * sn;
          }
          o[((size_t)(b * H_ + h) * S_ + s) * HD_ + hd] = (bf16)val;
        }
      }
  }
}

// ---------------------------------------------------------------------------
// Flash attention: q,k bf16 [B*H][S][HD], vt bf16 [B*H][HD][S],
// mask fp32 [B][S], ctx bf16 [B][S][Dm]. One block = (head, 64 q rows).
// ---------------------------------------------------------------------------
__global__ __launch_bounds__(256, 2) void flash_attn(
    const bf16* __restrict__ q, const bf16* __restrict__ k,
    const bf16* __restrict__ vt, const float* __restrict__ mask,
    bf16* __restrict__ ctx) {
  __shared__ __align__(16) bf16 Ks[64 * 64];
  __shared__ __align__(16) bf16 Vs[64 * 64];
  __shared__ __align__(16) bf16 Ps[4][16 * 64];

  const int tid = threadIdx.x;
  const int lane = tid & 63, wave = tid >> 6;
  const int c = lane & 15, quad = lane >> 4;
  const int bh = blockIdx.y, b = bh >> 4, h = bh & 15;
  const int q0 = blockIdx.x * 64;

  const bf16* qh = q + (size_t)bh * S_ * HD_;
  const bf16* kh = k + (size_t)bh * S_ * HD_;
  const bf16* vh = vt + (size_t)bh * HD_ * S_;
  const float* mrow = mask + (size_t)b * S_;

  // Q fragments (A layout), loaded once
  int qrow = q0 + wave * 16 + c;
  bf16x8 qa0 = *(const bf16x8*)(qh + (size_t)qrow * HD_ + quad * 8);
  bf16x8 qa1 = *(const bf16x8*)(qh + (size_t)qrow * HD_ + 32 + quad * 8);

  const f32x4 z4 = {0.f, 0.f, 0.f, 0.f};
  f32x4 o[4] = {z4, z4, z4, z4};
  float m_i[4], l_i[4];
#pragma unroll
  for (int r = 0; r < 4; ++r) { m_i[r] = -1e30f; l_i[r] = 0.f; }

  for (int k0 = 0; k0 < S_; k0 += 64) {
    __syncthreads();
#pragma unroll
    for (int it = 0; it < 2; ++it) {
      int idx = tid + it * 256;          // 0..511 16B chunks
      int row = idx >> 3, ch = idx & 7;  // 8 chunks per 64-elem row
      cp16(Ks + (size_t)idx * 8, kh + (size_t)(k0 + row) * HD_ + ch * 8);
      cp16(Vs + (size_t)idx * 8, vh + (size_t)row * S_ + k0 + ch * 8);
    }
    __syncthreads();

    // S = Q K^T (16 q rows x 64 kv cols per wave)
    f32x4 s[4];
    float mv[4];
#pragma unroll
    for (int tj = 0; tj < 4; ++tj) {
      bf16x8 kb0 = *(const bf16x8*)(Ks + (tj * 16 + c) * 64 + quad * 8);
      bf16x8 kb1 = *(const bf16x8*)(Ks + (tj * 16 + c) * 64 + 32 + quad * 8);
      s[tj] = MFMA(qa0, kb0, z4);
      s[tj] = MFMA(qa1, kb1, s[tj]);
      mv[tj] = mrow[k0 + tj * 16 + c];
    }
#pragma unroll
    for (int tj = 0; tj < 4; ++tj)
#pragma unroll
      for (int r = 0; r < 4; ++r) s[tj][r] = s[tj][r] * 0.125f + mv[tj];

    // online softmax per q row (row = quad*4 + r)
    float p[4][4];
#pragma unroll
    for (int r = 0; r < 4; ++r) {
      float rm = fmaxf(fmaxf(s[0][r], s[1][r]), fmaxf(s[2][r], s[3][r]));
#pragma unroll
      for (int off = 1; off < 16; off <<= 1) rm = fmaxf(rm, __shfl_xor(rm, off));
      float mnew = fmaxf(m_i[r], rm);
      float alpha = __expf(m_i[r] - mnew);
      float rs = 0.f;
#pragma unroll
      for (int tj = 0; tj < 4; ++tj) {
        float pv = __expf(s[tj][r] - mnew);
        rs += pv;  // denominator includes masked terms (matches reference)
        p[tj][r] = (mv[tj] < -1e-5f) ? 0.f : pv;
      }
#pragma unroll
      for (int off = 1; off < 16; off <<= 1) rs += __shfl_xor(rs, off);
      l_i[r] = l_i[r] * alpha + rs;
      m_i[r] = mnew;
#pragma unroll
      for (int tn = 0; tn < 4; ++tn) o[tn][r] *= alpha;
    }

    // P -> LDS (C layout -> A layout round trip), per-wave region
    bf16* pw = Ps[wave];
#pragma unroll
    for (int tj = 0; tj < 4; ++tj)
#pragma unroll
      for (int r = 0; r < 4; ++r)
        pw[(quad * 4 + r) * 64 + tj * 16 + c] = (bf16)p[tj][r];
    asm volatile("s_waitcnt lgkmcnt(0)" ::: "memory");
    bf16x8 pa0 = *(const bf16x8*)(pw + c * 64 + quad * 8);
    bf16x8 pa1 = *(const bf16x8*)(pw + c * 64 + 32 + quad * 8);

    // O += P V
#pragma unroll
    for (int tn = 0; tn < 4; ++tn) {
      bf16x8 vb0 = *(const bf16x8*)(Vs + (tn * 16 + c) * 64 + quad * 8);
      bf16x8 vb1 = *(const bf16x8*)(Vs + (tn * 16 + c) * 64 + 32 + quad * 8);
      o[tn] = MFMA(pa0, vb0, o[tn]);
      o[tn] = MFMA(pa1, vb1, o[tn]);
    }
  }

  // epilogue: O /= l, write ctx[b][s][h*64+hd]
#pragma unroll
  for (int r = 0; r < 4; ++r) {
    float inv = 1.0f / l_i[r];
    int qout = q0 + wave * 16 + quad * 4 + r;
    bf16* crow = ctx + ((size_t)(b * S_ + qout)) * DM_ + h * HD_;
#pragma unroll
    for (int tn = 0; tn < 4; ++tn) crow[tn * 16 + c] = (bf16)(o[tn][r] * inv);
  }
}

// ---------------------------------------------------------------------------
// Launch
// ---------------------------------------------------------------------------
extern "C" void kernel_launch(void* const* d_in, const int* in_sizes, int n_in,
                              void* d_out, int out_size, void* d_ws,
                              size_t ws_size, hipStream_t stream) {
  const float* hs   = (const float*)d_in[0];
  const float* mask = (const float*)d_in[1];
  const float* rope = (const float*)d_in[2];
  const float* Wq = (const float*)d_in[3];  const float* bq = (const float*)d_in[4];
  const float* Wk = (const float*)d_in[5];  const float* bk = (const float*)d_in[6];
  const float* Wv = (const float*)d_in[7];  const float* bv = (const float*)d_in[8];
  const float* Wo = (const float*)d_in[9];  const float* bo = (const float*)d_in[10];
  const float* g1 = (const float*)d_in[11]; const float* be1 = (const float*)d_in[12];
  const float* g2 = (const float*)d_in[13]; const float* be2 = (const float*)d_in[14];
  const float* W1 = (const float*)d_in[15]; const float* b1 = (const float*)d_in[16];
  const float* W2 = (const float*)d_in[17]; const float* b2 = (const float*)d_in[18];
  float* out = (float*)d_out;
  char* ws = (char*)d_ws;
  const size_t MB = 1ull << 20;

  // workspace layout (peak 152 MiB; later buffers reuse dead regions)
  bf16* Wqt = (bf16*)(ws + 0 * MB);      // [1024][1024]
  bf16* Wkt = (bf16*)(ws + 2 * MB);
  bf16* Wvt = (bf16*)(ws + 4 * MB);
  bf16* Wot = (bf16*)(ws + 6 * MB);
  bf16* W1t = (bf16*)(ws + 8 * MB);      // [8192][1024]  (16 MB)
  bf16* W2t = (bf16*)(ws + 24 * MB);     // [1024][4096]  (8 MB)
  bf16* xln = (bf16*)(ws + 32 * MB);     // [4096][1024]  (also yln later)
  float* hid = (float*)(ws + 40 * MB);   // [4096][1024] fp32 (16 MB)
  bf16* qr  = (bf16*)(ws + 56 * MB);     // [32][2048][64]
  bf16* kr  = (bf16*)(ws + 64 * MB);
  bf16* vb_ = (bf16*)(ws + 72 * MB);
  bf16* vtr = (bf16*)(ws + 80 * MB);     // [32][64][2048]
  bf16* ctx = (bf16*)(ws + 88 * MB);     // [4096][1024]
  bf16* hbf = (bf16*)(ws + 56 * MB);     // [4096][8192] reuses qr..ctx (dead)
  bf16* act = (bf16*)(ws + 120 * MB);    // [4096][4096]

  dim3 blk(256);
  dim3 tb(32, 8);

  // weight conversion + transpose
  transpose_f32_bf16<<<dim3(32, 32), tb, 0, stream>>>(Wq, Wqt, 1024, 1024);
  transpose_f32_bf16<<<dim3(32, 32), tb, 0, stream>>>(Wk, Wkt, 1024, 1024);
  transpose_f32_bf16<<<dim3(32, 32), tb, 0, stream>>>(Wv, Wvt, 1024, 1024);
  transpose_f32_bf16<<<dim3(32, 32), tb, 0, stream>>>(Wo, Wot, 1024, 1024);
  transpose_f32_bf16<<<dim3(256, 32), tb, 0, stream>>>(W1, W1t, 1024, 8192);
  transpose_f32_bf16<<<dim3(32, 128), tb, 0, stream>>>(W2, W2t, 4096, 1024);

  // LN1
  ln_bf16<<<4096, blk, 0, stream>>>(hs, g1, be1, xln);

  // QKV projections (fused RoPE for Q/K, heads layout)
  gemm_bt<0><<<dim3(8, 32), blk, 0, stream>>>(xln, Wqt, bq, rope, nullptr, qr, 1024, 1024);
  gemm_bt<0><<<dim3(8, 32), blk, 0, stream>>>(xln, Wkt, bk, rope, nullptr, kr, 1024, 1024);
  gemm_bt<1><<<dim3(8, 32), blk, 0, stream>>>(xln, Wvt, bv, nullptr, nullptr, vb_, 1024, 1024);

  // V -> V^T per head
  transpose_bf16<<<dim3(2, 64, 32), tb, 0, stream>>>(vb_, vtr, 2048, 64);

  // flash attention
  flash_attn<<<dim3(32, 32), blk, 0, stream>>>(qr, kr, vtr, mask, ctx);

  // Wo projection + residual -> hidden (fp32)
  gemm_bt<2><<<dim3(8, 32), blk, 0, stream>>>(ctx, Wot, bo, nullptr, hs, hid, 1024, 1024);

  // LN2 (reuses xln buffer)
  ln_bf16<<<4096, blk, 0, stream>>>(hid, g2, be2, xln);

  // W1 GEMM -> h
  gemm_bt<3><<<dim3(64, 32), blk, 0, stream>>>(xln, W1t, b1, nullptr, nullptr, hbf, 8192, 1024);

  // swiglu
  swiglu_kernel<<<8192, blk, 0, stream>>>(hbf, act);

  // W2 GEMM + residual -> out (fp32)
  gemm_bt<2><<<dim3(8, 32), blk, 0, stream>>>(act, W2t, b2, nullptr, hid, out, 1024, 4096);

  (void)in_sizes; (void)n_in; (void)out_size; (void)ws_size;
}

// Round 2
// 473.083 us; speedup vs baseline: 1.2434x; 1.2434x over previous
//
#include <hip/hip_runtime.h>
#include <cstdint>

// ---------------------------------------------------------------------------
// FM4Bio transformer layer on MI355X (gfx950).
// LN1 -> fused QKV GEMM (+RoPE, +1/8 into Q) -> flash attn (no-max softmax)
//   -> Wo GEMM (+resid) -> LN2 -> W1 GEMM (+fused swiglu) -> W2 GEMM (+resid)
// All LDS tiles XOR-swizzled at 16B-chunk granularity: bank-conflict-free
// ds_read_b128 while global_load_lds slots stay contiguous.
// ---------------------------------------------------------------------------

typedef __bf16 bf16;
typedef __bf16 bf16x8 __attribute__((ext_vector_type(8)));
typedef float f32x4 __attribute__((ext_vector_type(4)));

#define B_ 2
#define S_ 2048
#define DM_ 1024
#define H_ 16
#define HD_ 64
#define INTER_ 4096

#define MFMA(a, b, c) __builtin_amdgcn_mfma_f32_16x16x32_bf16(a, b, c, 0, 0, 0)

__device__ __forceinline__ void cp16(void* lds, const void* g) {
  __builtin_amdgcn_global_load_lds(
      (const __attribute__((address_space(1))) void*)(uintptr_t)g,
      (__attribute__((address_space(3))) void*)(uint32_t)(uintptr_t)lds,
      16, 0, 0);
}

// ---------------------------------------------------------------------------
// Weight transpose: in fp32 [K][N] -> out bf16 [N][K]
// ---------------------------------------------------------------------------
__global__ void transpose_f32_bf16(const float* __restrict__ in,
                                   bf16* __restrict__ out, int K, int N) {
  __shared__ float tile[32][33];
  int n0 = blockIdx.x * 32, k0 = blockIdx.y * 32;
  int tx = threadIdx.x, ty = threadIdx.y;  // 32 x 8
#pragma unroll
  for (int i = 0; i < 32; i += 8)
    tile[ty + i][tx] = in[(size_t)(k0 + ty + i) * N + n0 + tx];
  __syncthreads();
#pragma unroll
  for (int i = 0; i < 32; i += 8)
    out[(size_t)(n0 + ty + i) * K + k0 + tx] = (bf16)tile[tx][ty + i];
}

// W1 transpose with swiglu-interleave remap: orig col n (0..8191) ->
// row r = ((n&4095)>>3)*16 + ((n>>12)<<3) + (n&7).  Groups of 16 rows hold
// 8 h0-cols then the matching 8 h1-cols, so a 16-lane MFMA col-span pairs
// h0/h1 via shfl_xor(...,8) in the epilogue.
__global__ void transpose_w1(const float* __restrict__ in,
                             bf16* __restrict__ out) {
  __shared__ float tile[32][33];
  int n0 = blockIdx.x * 32, k0 = blockIdx.y * 32;
  int tx = threadIdx.x, ty = threadIdx.y;
#pragma unroll
  for (int i = 0; i < 32; i += 8)
    tile[ty + i][tx] = in[(size_t)(k0 + ty + i) * (2 * INTER_) + n0 + tx];
  __syncthreads();
#pragma unroll
  for (int i = 0; i < 32; i += 8) {
    int n = n0 + ty + i;
    int r = ((n & 4095) >> 3) * 16 + ((n >> 12) << 3) + (n & 7);
    out[(size_t)r * DM_ + k0 + tx] = (bf16)tile[tx][ty + i];
  }
}

// bf16 [K][N] -> bf16 [N][K], batched over blockIdx.z (V -> V^T per head)
__global__ void transpose_bf16(const bf16* __restrict__ in,
                               bf16* __restrict__ out, int K, int N) {
  __shared__ bf16 tile[32][33];
  const size_t mo = (size_t)blockIdx.z * K * N;
  int n0 = blockIdx.x * 32, k0 = blockIdx.y * 32;
  int tx = threadIdx.x, ty = threadIdx.y;
#pragma unroll
  for (int i = 0; i < 32; i += 8)
    tile[ty + i][tx] = in[mo + (size_t)(k0 + ty + i) * N + n0 + tx];
  __syncthreads();
#pragma unroll
  for (int i = 0; i < 32; i += 8)
    out[mo + (size_t)(n0 + ty + i) * K + k0 + tx] = tile[tx][ty + i];
}

// ---------------------------------------------------------------------------
// LayerNorm: fp32 [rows][1024] -> bf16 [rows][1024]
// ---------------------------------------------------------------------------
__global__ __launch_bounds__(256) void ln_bf16(const float* __restrict__ x,
                                               const float* __restrict__ g,
                                               const float* __restrict__ bta,
                                               bf16* __restrict__ out) {
  int row = blockIdx.x;
  int tid = threadIdx.x;
  const float4* xr = (const float4*)(x + (size_t)row * DM_);
  float4 v = xr[tid];
  float s1 = v.x + v.y + v.z + v.w;
  float s2 = v.x * v.x + v.y * v.y + v.z * v.z + v.w * v.w;
#pragma unroll
  for (int off = 32; off; off >>= 1) {
    s1 += __shfl_xor(s1, off);
    s2 += __shfl_xor(s2, off);
  }
  __shared__ float rA[4], rB[4];
  int wave = tid >> 6, lane = tid & 63;
  if (!lane) { rA[wave] = s1; rB[wave] = s2; }
  __syncthreads();
  float t1 = rA[0] + rA[1] + rA[2] + rA[3];
  float t2 = rB[0] + rB[1] + rB[2] + rB[3];
  float mean = t1 * (1.0f / DM_);
  float var = t2 * (1.0f / DM_) - mean * mean;
  float rstd = rsqrtf(var + 1e-5f);
  int col = tid * 4;
  float4 gv = ((const float4*)g)[tid];
  float4 bv = ((const float4*)bta)[tid];
  bf16* o = out + (size_t)row * DM_ + col;
  o[0] = (bf16)((v.x - mean) * rstd * gv.x + bv.x);
  o[1] = (bf16)((v.y - mean) * rstd * gv.y + bv.y);
  o[2] = (bf16)((v.z - mean) * rstd * gv.z + bv.z);
  o[3] = (bf16)((v.w - mean) * rstd * gv.w + bv.w);
}

// ---------------------------------------------------------------------------
// GEMM: C[M,N] = A[M,K](bf16) * Bt[N,K]^T(bf16), 128xBN tile, swizzled LDS.
// EPI 0: fused QKV (bias select, RoPE for q/k, 1/8 into q, heads layout)
// EPI 2: +bias +resid(fp32 [M,N]) -> fp32 [M,N]
// EPI 4: W1 + fused swiglu (interleaved W1t layout) -> bf16 [M,INTER]
// ---------------------------------------------------------------------------
template <int EPI, int BN>
__global__ __launch_bounds__(256, 2) void gemm_bt(
    const bf16* __restrict__ A, const bf16* __restrict__ Bt,
    const float* __restrict__ b0, const float* __restrict__ b1p,
    const float* __restrict__ b2p, const float* __restrict__ rope,
    const float* __restrict__ resid, void* __restrict__ outp, int N, int K) {
  constexpr int TM = (BN == 128) ? 4 : 2;
  __shared__ __align__(16) bf16 As[128 * 32];
  __shared__ __align__(16) bf16 Bs[BN * 32];
  const int tid = threadIdx.x;
  const int lane = tid & 63, wave = tid >> 6;
  const int c = lane & 15, quad = lane >> 4;
  const int wr = (BN == 128) ? (wave >> 1) : wave;
  const int wc = (BN == 128) ? (wave & 1) : 0;
  const int mbase = wr * (16 * TM), nbase = wc * 64;
  const int bm0 = blockIdx.y * 128, bn0 = blockIdx.x * BN;
  const int sw = (c >> 1) & 3;  // read-side chunk swizzle

  f32x4 acc[TM][4];
  const f32x4 z4 = {0.f, 0.f, 0.f, 0.f};
#pragma unroll
  for (int i = 0; i < TM; ++i)
#pragma unroll
    for (int j = 0; j < 4; ++j) acc[i][j] = z4;

  for (int k0 = 0; k0 < K; k0 += 32) {
    __syncthreads();
#pragma unroll
    for (int it = 0; it < 2; ++it) {  // A: 512 chunks
      int idx = tid + it * 256;
      int row = idx >> 2, chg = (idx & 3) ^ ((idx >> 3) & 3);
      cp16(As + (size_t)idx * 8, A + (size_t)(bm0 + row) * K + k0 + chg * 8);
    }
#pragma unroll
    for (int it = 0; it < BN / 64; ++it) {  // B: BN*4 chunks
      int idx = tid + it * 256;
      int row = idx >> 2, chg = (idx & 3) ^ ((idx >> 3) & 3);
      cp16(Bs + (size_t)idx * 8, Bt + (size_t)(bn0 + row) * K + k0 + chg * 8);
    }
    __syncthreads();
    bf16x8 af[TM], bfr[4];
#pragma unroll
    for (int ti = 0; ti < TM; ++ti)
      af[ti] = *(const bf16x8*)(As + (mbase + ti * 16 + c) * 32 + (quad ^ sw) * 8);
#pragma unroll
    for (int tj = 0; tj < 4; ++tj)
      bfr[tj] = *(const bf16x8*)(Bs + (nbase + tj * 16 + c) * 32 + (quad ^ sw) * 8);
#pragma unroll
    for (int ti = 0; ti < TM; ++ti)
#pragma unroll
      for (int tj = 0; tj < 4; ++tj)
        acc[ti][tj] = MFMA(af[ti], bfr[tj], acc[ti][tj]);
  }

  if constexpr (EPI == 2) {
    float* o = (float*)outp;
#pragma unroll
    for (int ti = 0; ti < TM; ++ti)
#pragma unroll
      for (int r = 0; r < 4; ++r) {
        int gm = bm0 + mbase + ti * 16 + quad * 4 + r;
        const float* rrow = resid + (size_t)gm * N;
        float* orow = o + (size_t)gm * N;
#pragma unroll
        for (int tj = 0; tj < 4; ++tj) {
          int gn = bn0 + nbase + tj * 16 + c;
          orow[gn] = acc[ti][tj][r] + b0[gn] + rrow[gn];
        }
      }
  } else if constexpr (EPI == 4) {
    bf16* act = (bf16*)outp;
#pragma unroll
    for (int ti = 0; ti < TM; ++ti)
#pragma unroll
      for (int r = 0; r < 4; ++r) {
        int gm = bm0 + mbase + ti * 16 + quad * 4 + r;
        bf16* arow = act + (size_t)gm * INTER_;
#pragma unroll
        for (int tj = 0; tj < 4; ++tj) {
          int gn = bn0 + nbase + tj * 16 + c;
          int g = gn >> 4, t = gn & 7, hi = (gn >> 3) & 1;
          float val = acc[ti][tj][r] + b0[g * 8 + t + (hi << 12)];
          float part = __shfl_xor(val, 8);
          if (!hi) {  // this lane holds h0; partner holds h1
            float sg = part / (1.0f + __expf(-part));
            arow[g * 8 + t] = (bf16)(val * sg);
          }
        }
      }
  } else {  // EPI 0: fused QKV
    bf16* o = (bf16*)outp;
#pragma unroll
    for (int ti = 0; ti < TM; ++ti)
#pragma unroll
      for (int r = 0; r < 4; ++r) {
        int gm = bm0 + mbase + ti * 16 + quad * 4 + r;
        int s = gm & (S_ - 1);
        int bb = gm >> 11;
#pragma unroll
        for (int tj = 0; tj < 4; ++tj) {
          int gn = bn0 + nbase + tj * 16 + c;
          int mtx = gn >> 10;  // 0=q 1=k 2=v
          const float* bp = (mtx == 0) ? b0 : (mtx == 1) ? b1p : b2p;
          int ci = gn & 1023;
          float val = acc[ti][tj][r] + bp[ci];
          if (mtx < 2) {
            int pj = (tj & 2) ? tj - 2 : tj + 2;
            int ci2 = (tj & 2) ? ci - 32 : ci + 32;
            float part = acc[ti][pj][r] + bp[ci2];
            if (!(tj & 2)) part = -part;
            float fr = rope[s * HD_ + (gn & 63)];
            float sn, cs;
            __sincosf(fr, &sn, &cs);
            val = val * cs + part * sn;
            if (mtx == 0) val *= 0.125f;  // fold 1/sqrt(HD) into Q
          }
          o[(size_t)mtx * (32 * S_ * HD_) +
            (((size_t)(bb * H_ + ((gn >> 6) & 15))) * S_ + s) * HD_ + (gn & 63)] =
              (bf16)val;
        }
      }
  }
}

// ---------------------------------------------------------------------------
// Flash attention: q(pre-scaled),k bf16 [B*H][S][HD], vt bf16 [B*H][HD][S],
// mask fp32 [B][S], ctx bf16 [B][S][Dm]. One block = (64 q rows, head).
// No-max softmax (scores bounded); l-reduction deferred past the K-loop.
// ---------------------------------------------------------------------------
__global__ __launch_bounds__(256, 4) void flash_attn(
    const bf16* __restrict__ q, const bf16* __restrict__ k,
    const bf16* __restrict__ vt, const float* __restrict__ mask,
    bf16* __restrict__ ctx) {
  __shared__ __align__(16) bf16 Ks[64 * 64];
  __shared__ __align__(16) bf16 Vs[64 * 64];
  __shared__ __align__(16) bf16 Ps[4][16 * 64];

  const int tid = threadIdx.x;
  const int lane = tid & 63, wave = tid >> 6;
  const int c = lane & 15, quad = lane >> 4;
  const int bh = blockIdx.y, b = bh >> 4, h = bh & 15;
  const int q0 = blockIdx.x * 64;
  const int csw = c & 7;  // read-side chunk swizzle

  const bf16* qh = q + (size_t)bh * S_ * HD_;
  const bf16* kh = k + (size_t)bh * S_ * HD_;
  const bf16* vh = vt + (size_t)bh * HD_ * S_;
  const float* mrow = mask + (size_t)b * S_;

  int qrow = q0 + wave * 16 + c;
  bf16x8 qa0 = *(const bf16x8*)(qh + (size_t)qrow * HD_ + quad * 8);
  bf16x8 qa1 = *(const bf16x8*)(qh + (size_t)qrow * HD_ + (quad + 4) * 8);

  const f32x4 z4 = {0.f, 0.f, 0.f, 0.f};
  f32x4 o[4] = {z4, z4, z4, z4};
  float l_i[4] = {0.f, 0.f, 0.f, 0.f};

  for (int k0 = 0; k0 < S_; k0 += 64) {
    __syncthreads();
#pragma unroll
    for (int it = 0; it < 2; ++it) {
      int idx = tid + it * 256;
      int row = idx >> 3, chg = (idx & 7) ^ (row & 7);
      cp16(Ks + (size_t)idx * 8, kh + (size_t)(k0 + row) * HD_ + chg * 8);
      cp16(Vs + (size_t)idx * 8, vh + (size_t)row * S_ + k0 + chg * 8);
    }
    __syncthreads();

    // S = Q K^T
    f32x4 s[4];
    float mv[4];
#pragma unroll
    for (int tj = 0; tj < 4; ++tj) {
      const bf16* kr = Ks + (tj * 16 + c) * 64;
      bf16x8 kb0 = *(const bf16x8*)(kr + (quad ^ csw) * 8);
      bf16x8 kb1 = *(const bf16x8*)(kr + ((quad + 4) ^ csw) * 8);
      s[tj] = MFMA(qa0, kb0, z4);
      s[tj] = MFMA(qa1, kb1, s[tj]);
      mv[tj] = mrow[k0 + tj * 16 + c];
    }

    // p = exp(s + mask); masked entries contribute to l but p := 0
    bf16* pw = Ps[wave];
#pragma unroll
    for (int tj = 0; tj < 4; ++tj) {
      bool msk = mv[tj] < -1e-5f;
#pragma unroll
      for (int r = 0; r < 4; ++r) {
        float e = __expf(s[tj][r] + mv[tj]);
        l_i[r] += e;
        float p = msk ? 0.f : e;
        int prow = quad * 4 + r;
        int pos = (tj * 2 + (c >> 3)) ^ (prow & 7);
        pw[prow * 64 + pos * 8 + (c & 7)] = (bf16)p;
      }
    }
    asm volatile("s_waitcnt lgkmcnt(0)" ::: "memory");
    bf16x8 pa0 = *(const bf16x8*)(pw + c * 64 + (quad ^ csw) * 8);
    bf16x8 pa1 = *(const bf16x8*)(pw + c * 64 + ((quad + 4) ^ csw) * 8);

    // O += P V
#pragma unroll
    for (int tn = 0; tn < 4; ++tn) {
      const bf16* vr = Vs + (tn * 16 + c) * 64;
      bf16x8 vb0 = *(const bf16x8*)(vr + (quad ^ csw) * 8);
      bf16x8 vb1 = *(const bf16x8*)(vr + ((quad + 4) ^ csw) * 8);
      o[tn] = MFMA(pa0, vb0, o[tn]);
      o[tn] = MFMA(pa1, vb1, o[tn]);
    }
  }

  // deferred 16-lane l reduction + epilogue
#pragma unroll
  for (int r = 0; r < 4; ++r) {
    float l = l_i[r];
#pragma unroll
    for (int off = 1; off < 16; off <<= 1) l += __shfl_xor(l, off);
    float inv = 1.0f / l;
    int qout = q0 + wave * 16 + quad * 4 + r;
    bf16* crow = ctx + ((size_t)(b * S_ + qout)) * DM_ + h * HD_;
#pragma unroll
    for (int tn = 0; tn < 4; ++tn) crow[tn * 16 + c] = (bf16)(o[tn][r] * inv);
  }
}

// ---------------------------------------------------------------------------
// Launch
// ---------------------------------------------------------------------------
extern "C" void kernel_launch(void* const* d_in, const int* in_sizes, int n_in,
                              void* d_out, int out_size, void* d_ws,
                              size_t ws_size, hipStream_t stream) {
  const float* hs   = (const float*)d_in[0];
  const float* mask = (const float*)d_in[1];
  const float* rope = (const float*)d_in[2];
  const float* Wq = (const float*)d_in[3];  const float* bq = (const float*)d_in[4];
  const float* Wk = (const float*)d_in[5];  const float* bk = (const float*)d_in[6];
  const float* Wv = (const float*)d_in[7];  const float* bv = (const float*)d_in[8];
  const float* Wo = (const float*)d_in[9];  const float* bo = (const float*)d_in[10];
  const float* g1 = (const float*)d_in[11]; const float* be1 = (const float*)d_in[12];
  const float* g2 = (const float*)d_in[13]; const float* be2 = (const float*)d_in[14];
  const float* W1 = (const float*)d_in[15]; const float* b1 = (const float*)d_in[16];
  const float* W2 = (const float*)d_in[17]; const float* b2 = (const float*)d_in[18];
  float* out = (float*)d_out;
  char* ws = (char*)d_ws;
  const size_t MB = 1ull << 20;

  // workspace layout (peak 128 MiB)
  bf16* Wqkvt = (bf16*)(ws + 0 * MB);    // [3072][1024]  (6 MB)
  bf16* Wot = (bf16*)(ws + 6 * MB);      // [1024][1024]  (2 MB)
  bf16* W1t = (bf16*)(ws + 8 * MB);      // [8192][1024] interleaved (16 MB)
  bf16* W2t = (bf16*)(ws + 24 * MB);     // [1024][4096]  (8 MB)
  bf16* xln = (bf16*)(ws + 32 * MB);     // [4096][1024]  (8 MB)
  float* hid = (float*)(ws + 40 * MB);   // [4096][1024] fp32 (16 MB)
  bf16* qkv = (bf16*)(ws + 56 * MB);     // 3 x [32][2048][64]  (24 MB)
  bf16* vtr = (bf16*)(ws + 80 * MB);     // [32][64][2048]  (8 MB)
  bf16* ctx = (bf16*)(ws + 88 * MB);     // [4096][1024]  (8 MB)
  bf16* act = (bf16*)(ws + 96 * MB);     // [4096][4096]  (32 MB)

  dim3 blk(256);
  dim3 tb(32, 8);

  // weight conversion + transpose
  transpose_f32_bf16<<<dim3(32, 32), tb, 0, stream>>>(Wq, Wqkvt, 1024, 1024);
  transpose_f32_bf16<<<dim3(32, 32), tb, 0, stream>>>(Wk, Wqkvt + (1 << 20), 1024, 1024);
  transpose_f32_bf16<<<dim3(32, 32), tb, 0, stream>>>(Wv, Wqkvt + (2 << 20), 1024, 1024);
  transpose_f32_bf16<<<dim3(32, 32), tb, 0, stream>>>(Wo, Wot, 1024, 1024);
  transpose_w1<<<dim3(256, 32), tb, 0, stream>>>(W1, W1t);
  transpose_f32_bf16<<<dim3(32, 128), tb, 0, stream>>>(W2, W2t, 4096, 1024);

  // LN1
  ln_bf16<<<4096, blk, 0, stream>>>(hs, g1, be1, xln);

  // fused QKV projection (RoPE q/k, 1/8 into q, heads layout)
  gemm_bt<0, 128><<<dim3(24, 32), blk, 0, stream>>>(
      xln, Wqkvt, bq, bk, bv, rope, nullptr, qkv, 3072, 1024);

  // V -> V^T per head
  transpose_bf16<<<dim3(2, 64, 32), tb, 0, stream>>>(
      qkv + (size_t)2 * 32 * S_ * HD_, vtr, 2048, 64);

  // flash attention
  flash_attn<<<dim3(32, 32), blk, 0, stream>>>(
      qkv, qkv + (size_t)32 * S_ * HD_, vtr, mask, ctx);

  // Wo projection + residual -> hidden (fp32)
  gemm_bt<2, 64><<<dim3(16, 32), blk, 0, stream>>>(
      ctx, Wot, bo, nullptr, nullptr, nullptr, hs, hid, 1024, 1024);

  // LN2
  ln_bf16<<<4096, blk, 0, stream>>>(hid, g2, be2, xln);

  // W1 GEMM + fused swiglu -> act
  gemm_bt<4, 128><<<dim3(64, 32), blk, 0, stream>>>(
      xln, W1t, b1, nullptr, nullptr, nullptr, nullptr, act, 8192, 1024);

  // W2 GEMM + residual -> out (fp32)
  gemm_bt<2, 64><<<dim3(16, 32), blk, 0, stream>>>(
      act, W2t, b2, nullptr, nullptr, nullptr, hid, out, 1024, 4096);

  (void)in_sizes; (void)n_in; (void)out_size; (void)ws_size;
}